// Round 9
// baseline (123.234 us; speedup 1.0000x reference)
//
#include <hip/hip_runtime.h>
#include <math.h>

#define LAYERS  8
#define FEAT    3072
#define NCLASS  10
#define DIM     4096
#define ST      66   // padded LDS row stride (floats)

typedef float v2f __attribute__((ext_vector_type(2)));
typedef float v4f __attribute__((ext_vector_type(4)));

__device__ __forceinline__ int px6c(int r) {
    int u = r ^ (r >> 1); u ^= u >> 2; u ^= u >> 4; return u & 63;
}
__device__ __forceinline__ int gray6(int r) { return (r ^ (r >> 1)) & 63; }

__device__ __forceinline__ float getc(const v2f v[32], int u) {
    return (u & 1) ? v[u >> 1].y : v[u >> 1].x;
}
__device__ __forceinline__ void setc(v2f v[32], int u, float x) {
    if (u & 1) v[u >> 1].y = x; else v[u >> 1].x = x;
}
__device__ __forceinline__ float bpermf(int addr, float x) {
    return __int_as_float(__builtin_amdgcn_ds_bpermute(addr, __float_as_int(x)));
}

// plain 6 register-qubit butterflies (packed v2f); reg bit p uses cl[off-p]/sl[off-p]
__device__ __forceinline__ void butterflies6(v2f v[32],
                                             const float* __restrict__ cl,
                                             const float* __restrict__ sl,
                                             int off) {
    {
        const float c = cl[off], s = sl[off];
        const v2f c2 = {c, c};
        const v2f ms = {-s, s};
#pragma unroll
        for (int i = 0; i < 32; ++i) {
            v2f a = v[i];
            v2f sw = {a.y, a.x};
            v[i] = a * c2 + sw * ms;   // (c*x - s*y, s*x + c*y)
        }
    }
#pragma unroll
    for (int p = 1; p < 6; ++p) {
        const float c = cl[off - p], s = sl[off - p];
        const v2f c2 = {c, c};
        const v2f s2 = {s, s};
#pragma unroll
        for (int i0 = 0; i0 < 32; ++i0) {
            if (i0 & (1 << (p - 1))) continue;
            const int i1 = i0 | (1 << (p - 1));
            v2f a = v[i0], e = v[i1];
            v[i0] = a * c2 - e * s2;
            v[i1] = a * s2 + e * c2;
        }
    }
}

// A-phase CONJUGATED by the deferred GrayA — packed form (verified round 8).
__device__ __forceinline__ void butterflies6_renamed(v2f v[32],
                                                     const float* __restrict__ cl,
                                                     const float* __restrict__ sl,
                                                     float psgn) {
    {
        const float c = cl[11], s = sl[11];
        const v2f c2 = {c, c};
        const v2f msA = {-s, s};
        const v2f msB = {s, -s};
#pragma unroll
        for (int k = 0; k < 32; ++k) {
            v2f a = v[k];
            v2f sw = {a.y, a.x};
            v[k] = a * c2 + sw * ((k & 1) ? msB : msA);
        }
    }
#pragma unroll
    for (int b = 1; b < 5; ++b) {
        const float c = cl[11 - b], s = sl[11 - b];
        const v2f c2 = {c, c};
#pragma unroll
        for (int m = 0; m < 32; ++m) {
            if (m & (1 << (b - 1))) continue;
            const int part = m ^ ((1 << b) - 1);
            const float sg = (m & (1 << b)) ? -s : s;
            const v2f sg2 = {sg, sg};
            const v2f A = v[m], E = v[part];
            const v2f Esw = {E.y, E.x};
            const v2f Asw = {A.y, A.x};
            v[m]    = A * c2 - Esw * sg2;
            v[part] = Asw * sg2 + E * c2;
        }
    }
    {
        const float c = cl[6];
        const float snl = psgn * sl[6];
        const v2f c2 = {c, c};
        const v2f sg2 = {snl, snl};
#pragma unroll
        for (int m = 0; m < 16; ++m) {
            const int part = m ^ 31;
            const v2f A = v[m], E = v[part];
            const v2f Esw = {E.y, E.x};
            const v2f Asw = {A.y, A.x};
            v[m]    = A * c2 - Esw * sg2;
            v[part] = Asw * sg2 + E * c2;
        }
    }
}

// D-blocks (all verified in round 8)
__device__ __forceinline__ void evenT(v2f v[32], float* __restrict__ L, int t) {
#pragma unroll
    for (int i = 0; i < 32; ++i)
        *(v2f*)(L + ST * t + 2 * i) = v[i];          // b64 rows, 2-way free
#pragma unroll
    for (int u = 0; u < 64; ++u)
        setc(v, u, L[t + ST * u]);                   // b32 cols, conflict-free
}

__device__ __forceinline__ void oddT(v2f v[32], float* __restrict__ L,
                                     int t, int bp, int bm) {
#pragma unroll
    for (int s = 0; s < 64; ++s) {                   // GrayA folded into stores
        const int g = gray6(s);                      // compile-time
        L[((g & 32) ? bm : bp) + ST * g] = getc(v, s);
    }
#pragma unroll
    for (int i = 0; i < 32; ++i)
        v[i] = *(const v2f*)(L + ST * t + 2 * i);    // b64 rows
}

__device__ __forceinline__ void grayB(v2f v[32], int A0, int A1) {
    float n[64];
#pragma unroll
    for (int r = 0; r < 64; ++r) {
        const int srcr = px6c(r);                    // compile-time
        n[r] = bpermf((srcr & 1) ? A1 : A0, getc(v, srcr));
    }
#pragma unroll
    for (int r = 0; r < 64; ++r)
        setc(v, r, n[r]);
}

__device__ __forceinline__ void scatterP(const v2f v[32], float* __restrict__ L, int gtl) {
#pragma unroll
    for (int i = 0; i < 32; ++i) {
        const int g0 = 64 * gray6(2 * i);
        const int g1 = 64 * (gray6(2 * i) ^ 1);
        L[g0 + gtl]        = v[i].x * v[i].x;        // 2-way, free
        L[g1 + (gtl ^ 32)] = v[i].y * v[i].y;
    }
}

__global__ __launch_bounds__(64, 1)
void qnn_kernel(const float* __restrict__ x,
                const float* __restrict__ ang,
                const float* __restrict__ W,
                const float* __restrict__ bias,
                float* __restrict__ out)
{
    __shared__ float ldsP[ST * 64];     // 16896 B each; reused for q[] in epilogue
    __shared__ float ldsQ[ST * 64];
    __shared__ float cst[96], snt[96];

    const int t  = threadIdx.x;         // 0..63, single wave; TWO states per wave
    const int b0 = 2 * blockIdx.x;
    const int b1 = b0 + 1;

    // ---- trig tables; single wave, in-order DS -> no barriers anywhere ----
    {
        float a0 = ang[t];
        cst[t] = cosf(a0);
        snt[t] = sinf(a0);
        if (t < 32) {
            float a1 = ang[64 + t];
            cst[64 + t] = cosf(a1);
            snt[64 + t] = sinf(a1);
        }
    }

    // ---- load both states in B layout: v[r] = psi[64r + t] (coalesced b32) ----
    v2f vP[32], vQ[32];
    {
        const float* xP = x + (size_t)b0 * FEAT;
        const float* xQ = x + (size_t)b1 * FEAT;
#pragma unroll
        for (int r = 0; r < 64; ++r) {
            if (r < FEAT / 64) {
                setc(vP, r, xP[64 * r + t]);
                setc(vQ, r, xQ[64 * r + t]);
            } else {
                setc(vP, r, 0.f);
                setc(vQ, r, 0.f);
            }
        }
    }

    // ---- ||x||^2 for both (normalization deferred: circuit is linear) ----
    float invP, invQ;
    {
        v2f sP = {0.f, 0.f}, sQ = {0.f, 0.f};
#pragma unroll
        for (int i = 0; i < 32; ++i) { sP += vP[i] * vP[i]; sQ += vQ[i] * vQ[i]; }
        float s0 = sP.x + sP.y, s1 = sQ.x + sQ.y;
#pragma unroll
        for (int o = 1; o < 64; o <<= 1) {
            s0 += __shfl_xor(s0, o, 64);
            s1 += __shfl_xor(s1, o, 64);
        }
        invP = 1.0f / s0;
        invQ = 1.0f / s1;
    }

    // ---- per-lane constants (identical for both states) ----
    int px = t ^ (t >> 1); px ^= px >> 2; px ^= px >> 4; px &= 63;  // px6(t)
    const int A0 = 4 * px;
    const int A1 = 4 * (px ^ 63);
    const int u0 = t & 1;
    const float psgn = u0 ? -1.f : 1.f;
    const int gtl = gray6(t);
    const int bp  = gtl + 32 * ST * u0;
    const int bm  = gtl - 32 * ST * u0;

    // ================== staggered pipeline: V_k(P) D_k(P) V_k(Q) D_k(Q) ==================
    // layer 0 (even, clean)
    butterflies6(vP, cst, snt, 5);            // V1(P)
    evenT(vP, ldsP, t);                       // D1(P)
    butterflies6(vQ, cst, snt, 5);            // V1(Q)  <- covers D1(P)
    evenT(vQ, ldsQ, t);                       // D1(Q)

#pragma unroll 1
    for (int p = 0; p < 3; ++p) {
        const float* cE = cst + (2 * p) * 12;         // even layer 2p (A-phase)
        const float* sE = snt + (2 * p) * 12;
        const float* cO = cst + (2 * p + 1) * 12;     // odd layer 2p+1
        const float* sO = snt + (2 * p + 1) * 12;
        const float* cN = cst + (2 * p + 2) * 12;     // next even layer
        const float* sN = snt + (2 * p + 2) * 12;

        butterflies6(vP, cE, sE, 11);                 // V: Aφ(even) — covers D(Q)
        butterflies6_renamed(vP, cO, sO, psgn);       //    + renamed Aφ(odd)
        oddT(vP, ldsP, t, bp, bm);                    // D: transpose + GrayA folded
        butterflies6(vQ, cE, sE, 11);                 // V(Q) — covers D(P)
        butterflies6_renamed(vQ, cO, sO, psgn);
        oddT(vQ, ldsQ, t, bp, bm);                    // D(Q)

        butterflies6(vP, cO, sO, 5);                  // V: Bφ(odd) — covers D(Q)
        grayB(vP, A0, A1);                            // D: bperm Gray
        butterflies6(vQ, cO, sO, 5);                  // V(Q) — covers D(P)
        grayB(vQ, A0, A1);                            // D(Q)

        butterflies6(vP, cN, sN, 5);                  // V: Bφ(next even)
        evenT(vP, ldsP, t);                           // D
        butterflies6(vQ, cN, sN, 5);                  // V(Q)
        evenT(vQ, ldsQ, t);                           // D(Q)
    }

    // tail: layers 6 (A-phase) + 7
    {
        const float* cE = cst + 6 * 12;
        const float* sE = snt + 6 * 12;
        const float* cO = cst + 7 * 12;
        const float* sO = snt + 7 * 12;

        butterflies6(vP, cE, sE, 11);
        butterflies6_renamed(vP, cO, sO, psgn);
        oddT(vP, ldsP, t, bp, bm);
        butterflies6(vQ, cE, sE, 11);
        butterflies6_renamed(vQ, cO, sO, psgn);
        oddT(vQ, ldsQ, t, bp, bm);

        butterflies6(vP, cO, sO, 5);
        scatterP(vP, ldsP, gtl);                      // Gray(7) folded into scatter
        butterflies6(vQ, cO, sO, 5);
        scatterP(vQ, ldsQ, gtl);
    }

    // ---- epilogue: shared-W dot products for both states ----
    float accP[NCLASS], accQ[NCLASS];
#pragma unroll
    for (int c = 0; c < NCLASS; ++c) { accP[c] = 0.f; accQ[c] = 0.f; }

#pragma unroll 2
    for (int k = 0; k < 16; ++k) {
        const v4f qP = *(const v4f*)(ldsP + 4 * t + 256 * k);   // b128, conflict-free
        const v4f qQ = *(const v4f*)(ldsQ + 4 * t + 256 * k);
        const float* wp = W + 4 * t + 256 * k;
#pragma unroll
        for (int c = 0; c < NCLASS; ++c) {
            const v4f w4 = *(const v4f*)(wp + c * DIM);          // shared by both states
            accP[c] += qP.x * w4.x + qP.y * w4.y + qP.z * w4.z + qP.w * w4.w;
            accQ[c] += qQ.x * w4.x + qQ.y * w4.y + qQ.z * w4.z + qQ.w * w4.w;
        }
    }

#pragma unroll
    for (int c = 0; c < NCLASS; ++c) {
        float a0 = accP[c], a1 = accQ[c];
#pragma unroll
        for (int o = 1; o < 64; o <<= 1) {
            a0 += __shfl_xor(a0, o, 64);
            a1 += __shfl_xor(a1, o, 64);
        }
        if (t == 0) {
            out[b0 * NCLASS + c] = fmaf(a0, invP, bias[c]);
            out[b1 * NCLASS + c] = fmaf(a1, invQ, bias[c]);
        }
    }
}

extern "C" void kernel_launch(void* const* d_in, const int* in_sizes, int n_in,
                              void* d_out, int out_size, void* d_ws, size_t ws_size,
                              hipStream_t stream) {
    const float* x    = (const float*)d_in[0];
    const float* ang  = (const float*)d_in[1];
    const float* W    = (const float*)d_in[2];
    const float* bias = (const float*)d_in[3];
    float* out = (float*)d_out;
    const int batch = in_sizes[0] / FEAT;   // 2048
    qnn_kernel<<<batch / 2, 64, 0, stream>>>(x, ang, W, bias, out);
}

// Round 10
// 116.089 us; speedup vs baseline: 1.0616x; 1.0616x over previous
//
#include <hip/hip_runtime.h>
#include <math.h>

#define LAYERS  8
#define FEAT    3072
#define NCLASS  10
#define DIM     4096
#define ST      68   // padded LDS row stride (floats); ST%4==0 -> b128-able, ST%32==4

typedef float v2f __attribute__((ext_vector_type(2)));
typedef float v4f __attribute__((ext_vector_type(4)));

// prefix-xor (inverse Gray) of 6-bit value; compile-time under unroll
__device__ __forceinline__ int px6c(int r) {
    int u = r ^ (r >> 1); u ^= u >> 2; u ^= u >> 4; return u & 63;
}
__device__ __forceinline__ int gray6(int r) { return (r ^ (r >> 1)) & 63; }

__device__ __forceinline__ float getc(const v2f v[32], int u) {
    return (u & 1) ? v[u >> 1].y : v[u >> 1].x;
}
__device__ __forceinline__ void setc(v2f v[32], int u, float x) {
    if (u & 1) v[u >> 1].y = x; else v[u >> 1].x = x;
}
__device__ __forceinline__ float bpermf(int addr, float x) {
    return __int_as_float(__builtin_amdgcn_ds_bpermute(addr, __float_as_int(x)));
}

// plain 6 register-qubit butterflies (packed v2f); reg bit p uses cl[off-p]/sl[off-p]
__device__ __forceinline__ void butterflies6(v2f v[32],
                                             const float* __restrict__ cl,
                                             const float* __restrict__ sl,
                                             int off) {
    {
        const float c = cl[off], s = sl[off];
        const v2f c2 = {c, c};
        const v2f ms = {-s, s};
#pragma unroll
        for (int i = 0; i < 32; ++i) {
            v2f a = v[i];
            v2f sw = {a.y, a.x};
            v[i] = a * c2 + sw * ms;   // (c*x - s*y, s*x + c*y)
        }
    }
#pragma unroll
    for (int p = 1; p < 6; ++p) {
        const float c = cl[off - p], s = sl[off - p];
        const v2f c2 = {c, c};
        const v2f s2 = {s, s};
#pragma unroll
        for (int i0 = 0; i0 < 32; ++i0) {
            if (i0 & (1 << (p - 1))) continue;
            const int i1 = i0 | (1 << (p - 1));
            v2f a = v[i0], e = v[i1];
            v[i0] = a * c2 - e * s2;
            v[i1] = a * s2 + e * c2;
        }
    }
}

// A-phase CONJUGATED by the deferred GrayA — packed form (verified rounds 7/8).
__device__ __forceinline__ void butterflies6_renamed(v2f v[32],
                                                     const float* __restrict__ cl,
                                                     const float* __restrict__ sl,
                                                     float psgn) {
    {
        const float c = cl[11], s = sl[11];
        const v2f c2 = {c, c};
        const v2f msA = {-s, s};
        const v2f msB = {s, -s};
#pragma unroll
        for (int k = 0; k < 32; ++k) {
            v2f a = v[k];
            v2f sw = {a.y, a.x};
            v[k] = a * c2 + sw * ((k & 1) ? msB : msA);
        }
    }
#pragma unroll
    for (int b = 1; b < 5; ++b) {
        const float c = cl[11 - b], s = sl[11 - b];
        const v2f c2 = {c, c};
#pragma unroll
        for (int m = 0; m < 32; ++m) {
            if (m & (1 << (b - 1))) continue;
            const int part = m ^ ((1 << b) - 1);
            const float sg = (m & (1 << b)) ? -s : s;
            const v2f sg2 = {sg, sg};
            const v2f A = v[m], E = v[part];
            const v2f Esw = {E.y, E.x};
            const v2f Asw = {A.y, A.x};
            v[m]    = A * c2 - Esw * sg2;
            v[part] = Asw * sg2 + E * c2;
        }
    }
    {
        const float c = cl[6];
        const float snl = psgn * sl[6];
        const v2f c2 = {c, c};
        const v2f sg2 = {snl, snl};
#pragma unroll
        for (int m = 0; m < 16; ++m) {
            const int part = m ^ 31;
            const v2f A = v[m], E = v[part];
            const v2f Esw = {E.y, E.x};
            const v2f Asw = {A.y, A.x};
            v[m]    = A * c2 - Esw * sg2;
            v[part] = Asw * sg2 + E * c2;
        }
    }
}

__global__ __launch_bounds__(64)
void qnn_kernel(const float* __restrict__ x,
                const float* __restrict__ ang,
                const float* __restrict__ W,
                const float* __restrict__ bias,
                float* __restrict__ out)
{
    __shared__ __attribute__((aligned(16))) float lds[ST * 64];  // 17408 B
    __shared__ float cst[96], snt[96];

    const int t = threadIdx.x;          // 0..63, single wave per block/state
    const int b = blockIdx.x;

    // ---- trig tables (96 angles); single wave, in-order DS -> no barrier ----
    {
        float a0 = ang[t];
        cst[t] = cosf(a0);
        snt[t] = sinf(a0);
        if (t < 32) {
            float a1 = ang[64 + t];
            cst[64 + t] = cosf(a1);
            snt[64 + t] = sinf(a1);
        }
    }

    // ---- load psi0 directly in B layout: v[r] = psi[64r + t] (coalesced b32) ----
    v2f v[32];
    {
        const float* xb = x + (size_t)b * FEAT;
#pragma unroll
        for (int r = 0; r < 64; ++r) {
            if (r < FEAT / 64) setc(v, r, xb[64 * r + t]);
            else               setc(v, r, 0.f);
        }
    }

    // ---- ||x||^2 (normalization deferred: circuit is linear) ----
    float invn2;
    {
        v2f s2 = {0.f, 0.f};
#pragma unroll
        for (int i = 0; i < 32; ++i) s2 += v[i] * v[i];
        float ss = s2.x + s2.y;
#pragma unroll
        for (int o = 1; o < 64; o <<= 1) ss += __shfl_xor(ss, o, 64);
        invn2 = 1.0f / ss;
    }

    // ---- phase-skew: anti-phase co-resident waves on a SIMD (lock-step breaker).
    //      Cost <= ~1152 cyc (~0.5 us) if useless; prize is V/D overlap. ----
    {
        const int ph = b & 3;
        if (ph == 1)      __builtin_amdgcn_s_sleep(6);   // ~384 cyc
        else if (ph == 2) __builtin_amdgcn_s_sleep(12);  // ~768 cyc
        else if (ph == 3) __builtin_amdgcn_s_sleep(18);  // ~1152 cyc
    }

    // ---- per-lane constants ----
    int px = t ^ (t >> 1); px ^= px >> 2; px ^= px >> 4; px &= 63;  // px6(t)
    const int A0 = 4 * px;                    // bpermute byte addrs (GrayB)
    const int A1 = 4 * (px ^ 63);
    const int u0 = t & 1;
    const float psgn = u0 ? -1.f : 1.f;       // parity sign for renamed b=5
    const int gtl = gray6(t);
    const int bp  = gtl + 32 * ST * u0;       // folded-GrayA store bases
    const int bm  = gtl - 32 * ST * u0;

    // ---- layer 0 (even, clean): B-phase, transpose B->A, A-phase ----
    {
        const float* cl = cst;
        const float* sl = snt;
        butterflies6(v, cl, sl, 5);                   // qubits 5..0 (reg = hi bits)
#pragma unroll
        for (int i = 0; i < 16; ++i) {                // b128 rows: quads (17t+i)%8, floor-free
            v4f q = {v[2 * i].x, v[2 * i].y, v[2 * i + 1].x, v[2 * i + 1].y};
            *(v4f*)(lds + ST * t + 4 * i) = q;
        }
#pragma unroll
        for (int u = 0; u < 64; ++u)                  // b32 cols: bank (t+4u)%32, 2-way free
            setc(v, u, lds[t + ST * u]);
        butterflies6(v, cl, sl, 11);                  // qubits 11..6 (reg = lo bits)
        // GrayA(0): deferred into layer 1
    }

#pragma unroll 1
    for (int p = 0; p < 4; ++p) {
        // ======== odd layer 2p+1: renamed A-phase, folded transpose, B-phase ========
        {
            const float* cl = cst + (2 * p + 1) * 12;
            const float* sl = snt + (2 * p + 1) * 12;

            butterflies6_renamed(v, cl, sl, psgn);

            // transpose A->B with GrayA folded into store addresses:
            // element (lane t, reg s) -> addr = ((gray6(s)&32)? bm : bp) + ST*gray6(s)
#pragma unroll
            for (int s = 0; s < 64; ++s) {
                const int g = gray6(s);                       // compile-time
                lds[((g & 32) ? bm : bp) + ST * g] = getc(v, s);  // 2-way free
            }
#pragma unroll
            for (int i = 0; i < 16; ++i) {                    // b128 rows, floor-free
                v4f q = *(const v4f*)(lds + ST * t + 4 * i);
                v[2 * i]     = (v2f){q.x, q.y};
                v[2 * i + 1] = (v2f){q.z, q.w};
            }

            butterflies6(v, cl, sl, 5);                       // qubits 5..0

            if (p < 3) {
                // GrayB (eager): new[r] = bperm(parity(src)?A1:A0, old[px6(r)])
                float n[64];
#pragma unroll
                for (int r = 0; r < 64; ++r) {
                    const int srcr = px6c(r);                 // compile-time
                    n[r] = bpermf((srcr & 1) ? A1 : A0, getc(v, srcr));
                }
#pragma unroll
                for (int r = 0; r < 64; ++r)
                    setc(v, r, n[r]);
            }
            // p == 3 (layer 7): final Gray folds into the epilogue scatter
        }

        if (p == 3) break;

        // ======== even layer 2p+2 (clean): B-phase, transpose B->A, A-phase ========
        {
            const float* cl = cst + (2 * p + 2) * 12;
            const float* sl = snt + (2 * p + 2) * 12;

            butterflies6(v, cl, sl, 5);
#pragma unroll
            for (int i = 0; i < 16; ++i) {
                v4f q = {v[2 * i].x, v[2 * i].y, v[2 * i + 1].x, v[2 * i + 1].y};
                *(v4f*)(lds + ST * t + 4 * i) = q;
            }
#pragma unroll
            for (int u = 0; u < 64; ++u)
                setc(v, u, lds[t + ST * u]);
            butterflies6(v, cl, sl, 11);
            // GrayA: deferred into next odd layer
        }
    }

    // ---- epilogue (B layout, Gray(7) folded): q[g(j)] = psi[j]^2,
    //      j = 64r + t, g(j) = 64*gray6(r) + (gray6(t) ^ 32*(r&1)) ----
#pragma unroll
    for (int i = 0; i < 32; ++i) {
        const int g0 = 64 * gray6(2 * i);
        const int g1 = 64 * (gray6(2 * i) ^ 1);
        lds[g0 + gtl]        = v[i].x * v[i].x;   // bank = gtl&31: 2-way, free
        lds[g1 + (gtl ^ 32)] = v[i].y * v[i].y;
    }

    float acc[NCLASS];
#pragma unroll
    for (int c = 0; c < NCLASS; ++c) acc[c] = 0.f;

#pragma unroll 1
    for (int k = 0; k < 16; ++k) {
        const v4f q4 = *(const v4f*)(lds + 4 * t + 256 * k);   // b128, floor-free
        const float* wp = W + 4 * t + 256 * k;
#pragma unroll
        for (int c = 0; c < NCLASS; ++c) {
            const v4f w4 = *(const v4f*)(wp + c * DIM);         // dwordx4, L2-resident
            acc[c] += q4.x * w4.x + q4.y * w4.y + q4.z * w4.z + q4.w * w4.w;
        }
    }

#pragma unroll
    for (int c = 0; c < NCLASS; ++c) {
        float a = acc[c];
#pragma unroll
        for (int o = 1; o < 64; o <<= 1) a += __shfl_xor(a, o, 64);
        if (t == 0) out[b * NCLASS + c] = fmaf(a, invn2, bias[c]);
    }
}

extern "C" void kernel_launch(void* const* d_in, const int* in_sizes, int n_in,
                              void* d_out, int out_size, void* d_ws, size_t ws_size,
                              hipStream_t stream) {
    const float* x    = (const float*)d_in[0];
    const float* ang  = (const float*)d_in[1];
    const float* W    = (const float*)d_in[2];
    const float* bias = (const float*)d_in[3];
    float* out = (float*)d_out;
    const int batch = in_sizes[0] / FEAT;   // 2048
    qnn_kernel<<<batch, 64, 0, stream>>>(x, ang, W, bias, out);
}

// Round 11
// 113.798 us; speedup vs baseline: 1.0829x; 1.0201x over previous
//
#include <hip/hip_runtime.h>
#include <math.h>

#define LAYERS  8
#define FEAT    3072
#define NCLASS  10
#define DIM     4096
#define ST      68   // padded LDS row stride (floats); ST%4==0 -> b128-able, ST%32==4

typedef float v2f __attribute__((ext_vector_type(2)));
typedef float v4f __attribute__((ext_vector_type(4)));

// prefix-xor (inverse Gray) of 6-bit value; compile-time under unroll
__device__ __forceinline__ int px6c(int r) {
    int u = r ^ (r >> 1); u ^= u >> 2; u ^= u >> 4; return u & 63;
}
__device__ __forceinline__ int gray6(int r) { return (r ^ (r >> 1)) & 63; }

__device__ __forceinline__ float getc(const v2f v[32], int u) {
    return (u & 1) ? v[u >> 1].y : v[u >> 1].x;
}
__device__ __forceinline__ void setc(v2f v[32], int u, float x) {
    if (u & 1) v[u >> 1].y = x; else v[u >> 1].x = x;
}
__device__ __forceinline__ float bpermf(int addr, float x) {
    return __int_as_float(__builtin_amdgcn_ds_bpermute(addr, __float_as_int(x)));
}

// plain 6 register-qubit butterflies (packed v2f); reg bit p uses cl[off-p]/sl[off-p]
__device__ __forceinline__ void butterflies6(v2f v[32],
                                             const float* __restrict__ cl,
                                             const float* __restrict__ sl,
                                             int off) {
    {
        const float c = cl[off], s = sl[off];
        const v2f c2 = {c, c};
        const v2f ms = {-s, s};
#pragma unroll
        for (int i = 0; i < 32; ++i) {
            v2f a = v[i];
            v2f sw = {a.y, a.x};
            v[i] = a * c2 + sw * ms;   // (c*x - s*y, s*x + c*y)
        }
    }
#pragma unroll
    for (int p = 1; p < 6; ++p) {
        const float c = cl[off - p], s = sl[off - p];
        const v2f c2 = {c, c};
        const v2f s2 = {s, s};
#pragma unroll
        for (int i0 = 0; i0 < 32; ++i0) {
            if (i0 & (1 << (p - 1))) continue;
            const int i1 = i0 | (1 << (p - 1));
            v2f a = v[i0], e = v[i1];
            v[i0] = a * c2 - e * s2;
            v[i1] = a * s2 + e * c2;
        }
    }
}

// A-phase CONJUGATED by the deferred GrayA — packed form (verified rounds 7/8).
__device__ __forceinline__ void butterflies6_renamed(v2f v[32],
                                                     const float* __restrict__ cl,
                                                     const float* __restrict__ sl,
                                                     float psgn) {
    {
        const float c = cl[11], s = sl[11];
        const v2f c2 = {c, c};
        const v2f msA = {-s, s};
        const v2f msB = {s, -s};
#pragma unroll
        for (int k = 0; k < 32; ++k) {
            v2f a = v[k];
            v2f sw = {a.y, a.x};
            v[k] = a * c2 + sw * ((k & 1) ? msB : msA);
        }
    }
#pragma unroll
    for (int b = 1; b < 5; ++b) {
        const float c = cl[11 - b], s = sl[11 - b];
        const v2f c2 = {c, c};
#pragma unroll
        for (int m = 0; m < 32; ++m) {
            if (m & (1 << (b - 1))) continue;
            const int part = m ^ ((1 << b) - 1);
            const float sg = (m & (1 << b)) ? -s : s;
            const v2f sg2 = {sg, sg};
            const v2f A = v[m], E = v[part];
            const v2f Esw = {E.y, E.x};
            const v2f Asw = {A.y, A.x};
            v[m]    = A * c2 - Esw * sg2;
            v[part] = Asw * sg2 + E * c2;
        }
    }
    {
        const float c = cl[6];
        const float snl = psgn * sl[6];
        const v2f c2 = {c, c};
        const v2f sg2 = {snl, snl};
#pragma unroll
        for (int m = 0; m < 16; ++m) {
            const int part = m ^ 31;
            const v2f A = v[m], E = v[part];
            const v2f Esw = {E.y, E.x};
            const v2f Asw = {A.y, A.x};
            v[m]    = A * c2 - Esw * sg2;
            v[part] = Asw * sg2 + E * c2;
        }
    }
}

__global__ __launch_bounds__(64)
void qnn_kernel(const float* __restrict__ x,
                const float* __restrict__ ang,
                const float* __restrict__ W,
                const float* __restrict__ bias,
                float* __restrict__ out)
{
    __shared__ __attribute__((aligned(16))) float lds[ST * 64];  // 17408 B
    __shared__ float cst[96], snt[96];

    const int t = threadIdx.x;          // 0..63, single wave per block/state
    const int b = blockIdx.x;

    // ---- trig tables (96 angles); single wave, in-order DS -> no barrier ----
    {
        float a0 = ang[t];
        cst[t] = cosf(a0);
        snt[t] = sinf(a0);
        if (t < 32) {
            float a1 = ang[64 + t];
            cst[64 + t] = cosf(a1);
            snt[64 + t] = sinf(a1);
        }
    }

    // ---- load psi0 directly in B layout: v[r] = psi[64r + t] (coalesced b32) ----
    v2f v[32];
    {
        const float* xb = x + (size_t)b * FEAT;
#pragma unroll
        for (int r = 0; r < 64; ++r) {
            if (r < FEAT / 64) setc(v, r, xb[64 * r + t]);
            else               setc(v, r, 0.f);
        }
    }

    // ---- ||x||^2 (normalization deferred: circuit is linear) ----
    float invn2;
    {
        v2f s2 = {0.f, 0.f};
#pragma unroll
        for (int i = 0; i < 32; ++i) s2 += v[i] * v[i];
        float ss = s2.x + s2.y;
#pragma unroll
        for (int o = 1; o < 64; o <<= 1) ss += __shfl_xor(ss, o, 64);
        invn2 = 1.0f / ss;
    }

    // ---- anti-lock-step skew keyed on the HW wave slot (distinct per SIMD):
    //      HW_ID (hwreg 4) bits [3:0] = wave_id. slot*768 cyc, <= ~2.2us once.
    //      blockIdx-keyed skew failed (co-resident blocks share b&3); this can't. ----
    {
        const int slot = __builtin_amdgcn_s_getreg(4 | (0 << 6) | (3 << 11)) & 7;
#pragma unroll 1
        for (int i = 0; i < slot; ++i) __builtin_amdgcn_s_sleep(12);   // 12*64 cyc
    }

    // ---- per-lane constants ----
    int px = t ^ (t >> 1); px ^= px >> 2; px ^= px >> 4; px &= 63;  // px6(t)
    const int A0 = 4 * px;                    // bpermute byte addrs (GrayB)
    const int A1 = 4 * (px ^ 63);
    const int u0 = t & 1;
    const float psgn = u0 ? -1.f : 1.f;       // parity sign for renamed b=5
    const int gtl = gray6(t);
    const int bp  = gtl + 32 * ST * u0;       // folded-GrayA store bases
    const int bm  = gtl - 32 * ST * u0;

    // ---- layer 0 (even, clean): B-phase, transpose B->A, A-phase ----
    {
        const float* cl = cst;
        const float* sl = snt;
        butterflies6(v, cl, sl, 5);                   // qubits 5..0 (reg = hi bits)
#pragma unroll
        for (int i = 0; i < 16; ++i) {                // b128 rows: quads (17t+i)%8, floor-free
            v4f q = {v[2 * i].x, v[2 * i].y, v[2 * i + 1].x, v[2 * i + 1].y};
            *(v4f*)(lds + ST * t + 4 * i) = q;
        }
#pragma unroll
        for (int u = 0; u < 64; ++u)                  // b32 cols: bank (t+4u)%32, 2-way free
            setc(v, u, lds[t + ST * u]);
        butterflies6(v, cl, sl, 11);                  // qubits 11..6 (reg = lo bits)
        // GrayA(0): deferred into layer 1
    }

#pragma unroll 1
    for (int p = 0; p < 4; ++p) {
        // ======== odd layer 2p+1: renamed A-phase, folded transpose, B-phase ========
        {
            const float* cl = cst + (2 * p + 1) * 12;
            const float* sl = snt + (2 * p + 1) * 12;

            butterflies6_renamed(v, cl, sl, psgn);

            // transpose A->B with GrayA folded into store addresses:
            // element (lane t, reg s) -> addr = ((gray6(s)&32)? bm : bp) + ST*gray6(s)
#pragma unroll
            for (int s = 0; s < 64; ++s) {
                const int g = gray6(s);                       // compile-time
                lds[((g & 32) ? bm : bp) + ST * g] = getc(v, s);  // 2-way free
            }
#pragma unroll
            for (int i = 0; i < 16; ++i) {                    // b128 rows, floor-free
                v4f q = *(const v4f*)(lds + ST * t + 4 * i);
                v[2 * i]     = (v2f){q.x, q.y};
                v[2 * i + 1] = (v2f){q.z, q.w};
            }

            butterflies6(v, cl, sl, 5);                       // qubits 5..0

            if (p < 3) {
                // GrayB (eager): new[r] = bperm(parity(src)?A1:A0, old[px6(r)])
                float n[64];
#pragma unroll
                for (int r = 0; r < 64; ++r) {
                    const int srcr = px6c(r);                 // compile-time
                    n[r] = bpermf((srcr & 1) ? A1 : A0, getc(v, srcr));
                }
#pragma unroll
                for (int r = 0; r < 64; ++r)
                    setc(v, r, n[r]);
            }
            // p == 3 (layer 7): final Gray folds into the epilogue scatter
        }

        if (p == 3) break;

        // ======== even layer 2p+2 (clean): B-phase, transpose B->A, A-phase ========
        {
            const float* cl = cst + (2 * p + 2) * 12;
            const float* sl = snt + (2 * p + 2) * 12;

            butterflies6(v, cl, sl, 5);
#pragma unroll
            for (int i = 0; i < 16; ++i) {
                v4f q = {v[2 * i].x, v[2 * i].y, v[2 * i + 1].x, v[2 * i + 1].y};
                *(v4f*)(lds + ST * t + 4 * i) = q;
            }
#pragma unroll
            for (int u = 0; u < 64; ++u)
                setc(v, u, lds[t + ST * u]);
            butterflies6(v, cl, sl, 11);
            // GrayA: deferred into next odd layer
        }
    }

    // ---- epilogue (B layout, Gray(7) folded): q[g(j)] = psi[j]^2,
    //      j = 64r + t, g(j) = 64*gray6(r) + (gray6(t) ^ 32*(r&1)) ----
#pragma unroll
    for (int i = 0; i < 32; ++i) {
        const int g0 = 64 * gray6(2 * i);
        const int g1 = 64 * (gray6(2 * i) ^ 1);
        lds[g0 + gtl]        = v[i].x * v[i].x;   // bank = gtl&31: 2-way, free
        lds[g1 + (gtl ^ 32)] = v[i].y * v[i].y;
    }

    float acc[NCLASS];
#pragma unroll
    for (int c = 0; c < NCLASS; ++c) acc[c] = 0.f;

#pragma unroll 1
    for (int k = 0; k < 16; ++k) {
        const v4f q4 = *(const v4f*)(lds + 4 * t + 256 * k);   // b128, floor-free
        const float* wp = W + 4 * t + 256 * k;
#pragma unroll
        for (int c = 0; c < NCLASS; ++c) {
            const v4f w4 = *(const v4f*)(wp + c * DIM);         // dwordx4, L2-resident
            acc[c] += q4.x * w4.x + q4.y * w4.y + q4.z * w4.z + q4.w * w4.w;
        }
    }

#pragma unroll
    for (int c = 0; c < NCLASS; ++c) {
        float a = acc[c];
#pragma unroll
        for (int o = 1; o < 64; o <<= 1) a += __shfl_xor(a, o, 64);
        if (t == 0) out[b * NCLASS + c] = fmaf(a, invn2, bias[c]);
    }
}

extern "C" void kernel_launch(void* const* d_in, const int* in_sizes, int n_in,
                              void* d_out, int out_size, void* d_ws, size_t ws_size,
                              hipStream_t stream) {
    const float* x    = (const float*)d_in[0];
    const float* ang  = (const float*)d_in[1];
    const float* W    = (const float*)d_in[2];
    const float* bias = (const float*)d_in[3];
    float* out = (float*)d_out;
    const int batch = in_sizes[0] / FEAT;   // 2048
    qnn_kernel<<<batch, 64, 0, stream>>>(x, ang, W, bias, out);
}